// Round 5
// baseline (906.917 us; speedup 1.0000x reference)
//
#include <hip/hip_runtime.h>
#include <hip/hip_bf16.h>

#define N_NODES 100000
#define N_EDGES 3200000
#define D 256
#define RSH 8
#define RPB 256                                  // rows per bucket = 1<<RSH
#define NB ((N_NODES + RPB - 1) / RPB)           // 391 coarse buckets
#define FILL_CH 8192                             // edges per block in bin/hist
#define NBLK_E ((N_EDGES + FILL_CH - 1) / FILL_CH)  // 391

typedef __attribute__((ext_vector_type(8))) short short8;   // 8 bf16 (4 VGPRs)
typedef __attribute__((ext_vector_type(4))) float floatx4;  // MFMA C/D

__device__ __forceinline__ unsigned short f32_to_bf16_rne(float f) {
    unsigned int u = __float_as_uint(f);
    u += 0x7FFFu + ((u >> 16) & 1u);
    return (unsigned short)(u >> 16);
}
__device__ __forceinline__ float bf16_bits_to_f32(unsigned short b) {
    return __uint_as_float(((unsigned int)b) << 16);
}
__device__ __forceinline__ float blo(unsigned int x) { return __uint_as_float(x << 16); }
__device__ __forceinline__ float bhi(unsigned int x) { return __uint_as_float(x & 0xFFFF0000u); }

// ---------------- W (fp32 [K][N]) -> bf16 MFMA-B-fragment order --------------
__global__ __launch_bounds__(256) void convert_w_k(const float* __restrict__ w,
                                                   unsigned short* __restrict__ wsw) {
    int t = blockIdx.x * 256 + threadIdx.x;
    int j     = t & 7;
    int lane  = (t >> 3) & 63;
    int kstep = (t >> 9) & 7;
    int ntile = t >> 12;
    int k = kstep * 32 + (lane >> 4) * 8 + j;
    int n = ntile * 16 + (lane & 15);
    wsw[t] = f32_to_bf16_rne(w[k * D + n]);
}

// ---------------- xw = x @ W (bf16 MFMA), NO LDS -----------------------------
// B-frags read straight from wsw (128 KB, L1/L2-resident, same addrs for all
// waves on a CU). A-frags for all 8 ksteps held in 32 VGPRs. One acc at a
// time -> VGPR ~70, 8 waves/SIMD (vs 1 block/CU with the 128 KiB LDS version).
__global__ __launch_bounds__(256, 4) void gemm_xw_k(const float* __restrict__ x,
                                                    const unsigned short* __restrict__ wsw,
                                                    unsigned short* __restrict__ xwb) {
    const int tid  = threadIdx.x;
    const int lane = tid & 63;
    const int wave = tid >> 6;
    const int q    = lane >> 4;
    const int ml   = lane & 15;
    const long rowBase = (long)blockIdx.x * 64 + wave * 16;
    long arow = rowBase + ml;
    if (arow >= N_NODES) arow = 0;
    const float* xr = x + arow * (long)D;

    // load + convert all A fragments (8 ksteps x 8 bf16 = 32 VGPRs)
    short8 af[8];
#pragma unroll
    for (int ks = 0; ks < 8; ++ks) {
        const float4 a0 = *(const float4*)(xr + ks * 32 + q * 8);
        const float4 a1 = *(const float4*)(xr + ks * 32 + q * 8 + 4);
        af[ks][0] = (short)f32_to_bf16_rne(a0.x);
        af[ks][1] = (short)f32_to_bf16_rne(a0.y);
        af[ks][2] = (short)f32_to_bf16_rne(a0.z);
        af[ks][3] = (short)f32_to_bf16_rne(a0.w);
        af[ks][4] = (short)f32_to_bf16_rne(a1.x);
        af[ks][5] = (short)f32_to_bf16_rne(a1.y);
        af[ks][6] = (short)f32_to_bf16_rne(a1.z);
        af[ks][7] = (short)f32_to_bf16_rne(a1.w);
    }

    const short8* wf = (const short8*)wsw;

#pragma unroll 4
    for (int nt = 0; nt < 16; ++nt) {
        floatx4 acc = (floatx4){0.f, 0.f, 0.f, 0.f};
#pragma unroll
        for (int ks = 0; ks < 8; ++ks) {
            acc = __builtin_amdgcn_mfma_f32_16x16x32_bf16(
                af[ks], wf[(nt * 8 + ks) * 64 + lane], acc, 0, 0, 0);
        }
#pragma unroll
        for (int r = 0; r < 4; ++r) {
            long orow = rowBase + q * 4 + r;
            if (orow < N_NODES)
                xwb[orow * (long)D + nt * 16 + ml] = f32_to_bf16_rne(acc[r]);
        }
    }
}

// ---------------- zero the bucket counters -----------------------------------
__global__ __launch_bounds__(256) void zero_counts_k(int* __restrict__ counts) {
    int i = blockIdx.x * 256 + threadIdx.x;
    if (i < NB) counts[i] = 0;
}

// ---------------- coarse-bucket histogram (LDS-aggregated) -------------------
__global__ __launch_bounds__(256) void bhist_k(const int* __restrict__ erow,
                                               int* __restrict__ counts) {
    __shared__ int h[NB];
    const int tid = threadIdx.x;
    for (int i = tid; i < NB; i += 256) h[i] = 0;
    __syncthreads();
    const int s = blockIdx.x * FILL_CH;
    const int e = min(s + FILL_CH, N_EDGES);
    for (int i = s + tid; i < e; i += 256) atomicAdd(&h[erow[i] >> RSH], 1);
    __syncthreads();
    for (int i = tid; i < NB; i += 256)
        if (h[i] > 0) atomicAdd(&counts[i], h[i]);
}

// ---------------- scan NB bucket counts (1 block of 1024) --------------------
__global__ __launch_bounds__(1024) void bscan_k(const int* __restrict__ counts,
                                                int* __restrict__ bbase,
                                                int* __restrict__ bcursor) {
    __shared__ int sc[1024];
    const int t = threadIdx.x;
    int v = (t < NB) ? counts[t] : 0;
    sc[t] = v;
    __syncthreads();
    for (int o = 1; o < 1024; o <<= 1) {
        int add = (t >= o) ? sc[t - o] : 0;
        __syncthreads();
        sc[t] += add;
        __syncthreads();
    }
    int excl = sc[t] - v;
    if (t < NB) { bbase[t] = excl; bcursor[t] = excl; }
    if (t == NB - 1) bbase[NB] = sc[t];
}

// ---------------- bin edges into coarse buckets (packed u64 records) ---------
// rec = row_local<<33 | val_bf16<<17 | col
__global__ __launch_bounds__(256) void binfill_k(const int* __restrict__ erow,
                                                 const int* __restrict__ ecol,
                                                 const float* __restrict__ eval,
                                                 int* __restrict__ bcursor,
                                                 unsigned long long* __restrict__ recs) {
    __shared__ int h[NB];
    __shared__ int lcur[NB];
    const int tid = threadIdx.x;
    for (int i = tid; i < NB; i += 256) h[i] = 0;
    __syncthreads();
    const int s = blockIdx.x * FILL_CH;
    const int e = min(s + FILL_CH, N_EDGES);
    for (int i = s + tid; i < e; i += 256) atomicAdd(&h[erow[i] >> RSH], 1);
    __syncthreads();
    for (int i = tid; i < NB; i += 256) {
        int cnt = h[i];
        lcur[i] = (cnt > 0) ? atomicAdd(&bcursor[i], cnt) : 0;
    }
    __syncthreads();
    for (int i = s + tid; i < e; i += 256) {
        int r = erow[i];
        int b = r >> RSH;
        int pos = atomicAdd(&lcur[b], 1);
        unsigned long long rec =
            ((unsigned long long)(r & (RPB - 1)) << 33) |
            ((unsigned long long)f32_to_bf16_rne(eval[i]) << 17) |
            (unsigned int)ecol[i];
        recs[pos] = rec;
    }
}

// ---------------- per-bucket counting sort to full row order -----------------
// one block per bucket (391 blocks); 256 threads = 256 rows/bucket.
__global__ __launch_bounds__(256) void bsort_k(const int* __restrict__ bbase,
                                               const unsigned long long* __restrict__ recs,
                                               int* __restrict__ offsets,
                                               unsigned int* __restrict__ cs,
                                               unsigned short* __restrict__ vs) {
    __shared__ int hist[RPB];
    __shared__ int cur[RPB];
    __shared__ int sc[RPB];
    const int t = threadIdx.x;
    const int b = blockIdx.x;
    const int base = bbase[b];
    const int endp = bbase[b + 1];

    hist[t] = 0;
    __syncthreads();
    for (int i = base + t; i < endp; i += 256)
        atomicAdd(&hist[(int)(recs[i] >> 33)], 1);
    __syncthreads();

    int hv = hist[t];
    sc[t] = hv;
    __syncthreads();
    for (int o = 1; o < RPB; o <<= 1) {
        int add = (t >= o) ? sc[t - o] : 0;
        __syncthreads();
        sc[t] += add;
        __syncthreads();
    }
    int excl = sc[t] - hv;
    cur[t] = excl;
    {
        int r = (b << RSH) + t;
        if (r <= N_NODES) offsets[r] = base + excl;
    }
    __syncthreads();

    for (int i = base + t; i < endp; i += 256) {
        unsigned long long rec = recs[i];
        int rl = (int)(rec >> 33);
        int pos = base + atomicAdd(&cur[rl], 1);
        cs[pos] = (unsigned int)(rec & 0x1FFFFu);
        vs[pos] = (unsigned short)((rec >> 17) & 0xFFFFu);
    }
}

// ---------------- segment reduce: out[r] = relu(sum v * xwb[c]) --------------
// one wave per node; paired gathers (2 edges per uint4 wave-load). Depth-4
// rotating software pipeline keeps 3-4 gathers in flight; launch_bounds(256,8)
// pins VGPR<=64 so occupancy stays at 8 waves/SIMD while allowing the
// pipeline registers (round-4 failure: compiler chose VGPR=32 and serialized).
__global__ __launch_bounds__(256, 8) void aggregate_k(const unsigned short* __restrict__ xwb,
                                                      const int* __restrict__ offsets,
                                                      const unsigned int* __restrict__ cs,
                                                      const unsigned short* __restrict__ vs,
                                                      float* __restrict__ out) {
    const int wave = threadIdx.x >> 6;
    const int lane = threadIdx.x & 63;
    const int r = blockIdx.x * 4 + wave;
    if (r >= N_NODES) return;

    const int start = offsets[r];
    const int end   = offsets[r + 1];
    const int half  = lane >> 5;
    const int hl    = lane & 31;

    float acc[8];
#pragma unroll
    for (int k = 0; k < 8; ++k) acc[k] = 0.f;

    for (int jb = start; jb < end; jb += 64) {
        int j = jb + lane;
        unsigned int c = 0;
        float v = 0.f;
        if (j < end) {
            c = cs[j];
            v = bf16_bits_to_f32(vs[j]);
        }
        const int cnt = min(64, end - jb);
        const int pairs = (cnt + 1) >> 1;
        const int pairs4 = (pairs + 3) & ~3;

        uint4 q[4];
        float b[4];

#define SLOT_LOAD(d, tt)                                                       \
        {                                                                      \
            int src = 2 * (tt) + half;                                         \
            int srcc = min(src, cnt - 1);                                      \
            unsigned int bc = (unsigned int)__shfl((int)c, srcc);              \
            float bb = __shfl(v, srcc);                                        \
            b[d] = (src < cnt) ? bb : 0.f;                                     \
            q[d] = *((const uint4*)(xwb + (size_t)bc * D) + hl);               \
        }
#define FMA8(d)                                                                \
        acc[0] += b[d] * blo(q[d].x); acc[1] += b[d] * bhi(q[d].x);            \
        acc[2] += b[d] * blo(q[d].y); acc[3] += b[d] * bhi(q[d].y);            \
        acc[4] += b[d] * blo(q[d].z); acc[5] += b[d] * bhi(q[d].z);            \
        acc[6] += b[d] * blo(q[d].w); acc[7] += b[d] * bhi(q[d].w);

        SLOT_LOAD(0, 0)
        SLOT_LOAD(1, 1)
        SLOT_LOAD(2, 2)
        SLOT_LOAD(3, 3)

        for (int t = 0; t < pairs4; t += 4) {
#pragma unroll
            for (int d = 0; d < 4; ++d) {
                FMA8(d)
                if (t + 4 + d < pairs4) {       // wave-uniform guard
                    SLOT_LOAD(d, t + 4 + d)
                } else {
                    b[d] = 0.f;                 // stale q[d] * 0 = 0
                }
            }
        }
#undef SLOT_LOAD
#undef FMA8
    }

    // combine even/odd halves (lane l and l^32 hold the same columns)
#pragma unroll
    for (int k = 0; k < 8; ++k) acc[k] += __shfl_xor(acc[k], 32);

    // redistribute: lane l writes cols 4l..4l+3 (source lane l>>1)
    const int s = lane >> 1;
    const int par = lane & 1;
    float4 o;
    {
        float a0 = __shfl(acc[0], s), b0 = __shfl(acc[4], s);
        float a1 = __shfl(acc[1], s), b1 = __shfl(acc[5], s);
        float a2 = __shfl(acc[2], s), b2 = __shfl(acc[6], s);
        float a3 = __shfl(acc[3], s), b3 = __shfl(acc[7], s);
        o.x = par ? b0 : a0;
        o.y = par ? b1 : a1;
        o.z = par ? b2 : a2;
        o.w = par ? b3 : a3;
    }
    o.x = fmaxf(o.x, 0.f);
    o.y = fmaxf(o.y, 0.f);
    o.z = fmaxf(o.z, 0.f);
    o.w = fmaxf(o.w, 0.f);
    ((float4*)(out + (size_t)r * D))[lane] = o;
}

extern "C" void kernel_launch(void* const* d_in, const int* in_sizes, int n_in,
                              void* d_out, int out_size, void* d_ws, size_t ws_size,
                              hipStream_t stream) {
    const float* x    = (const float*)d_in[0];
    const float* w    = (const float*)d_in[1];
    const int*   erow = (const int*)d_in[2];
    const int*   ecol = (const int*)d_in[3];
    const float* eval = (const float*)d_in[4];
    float* out = (float*)d_out;

    // ---- workspace layout (~96.6 MB) ----
    char* p = (char*)d_ws;
    auto align = [](size_t v) { return (v + 255) & ~(size_t)255; };

    unsigned short* xwb = (unsigned short*)p;                  // 51.2 MB
    p += align((size_t)N_NODES * D * sizeof(unsigned short));
    unsigned short* wsw = (unsigned short*)p;                  // 128 KiB
    p += align((size_t)D * D * sizeof(unsigned short));
    int* bcounts = (int*)p;  p += align((size_t)NB * sizeof(int));
    int* bbase   = (int*)p;  p += align((size_t)(NB + 1) * sizeof(int));
    int* bcursor = (int*)p;  p += align((size_t)NB * sizeof(int));
    unsigned long long* recs = (unsigned long long*)p;         // 25.6 MB
    p += align((size_t)N_EDGES * sizeof(unsigned long long));
    unsigned int*   cs = (unsigned int*)p;    p += align((size_t)N_EDGES * 4);  // 12.8 MB
    unsigned short* vs = (unsigned short*)p;  p += align((size_t)N_EDGES * 2);  // 6.4 MB
    int* offsets = (int*)p;  p += align((size_t)(N_NODES + 1) * sizeof(int));   // 400 KB

    convert_w_k<<<(D * D) / 256, 256, 0, stream>>>(w, wsw);
    gemm_xw_k<<<(N_NODES + 63) / 64, 256, 0, stream>>>(x, wsw, xwb);
    zero_counts_k<<<(NB + 255) / 256, 256, 0, stream>>>(bcounts);
    bhist_k<<<NBLK_E, 256, 0, stream>>>(erow, bcounts);
    bscan_k<<<1, 1024, 0, stream>>>(bcounts, bbase, bcursor);
    binfill_k<<<NBLK_E, 256, 0, stream>>>(erow, ecol, eval, bcursor, recs);
    bsort_k<<<NB, 256, 0, stream>>>(bbase, recs, offsets, cs, vs);
    aggregate_k<<<(N_NODES + 3) / 4, 256, 0, stream>>>(xwb, offsets, cs, vs, out);
}

// Round 6
// 617.241 us; speedup vs baseline: 1.4693x; 1.4693x over previous
//
#include <hip/hip_runtime.h>
#include <hip/hip_bf16.h>

#define N_NODES 100000
#define N_EDGES 3200000
#define D 256
#define RSH 8
#define RPB 256                                  // rows per bucket = 1<<RSH
#define NB ((N_NODES + RPB - 1) / RPB)           // 391 coarse buckets
#define FILL_CH 16384                            // edges per block in bin/hist
#define NBLK_E ((N_EDGES + FILL_CH - 1) / FILL_CH)  // 196

typedef __attribute__((ext_vector_type(8))) short short8;   // 8 bf16 (4 VGPRs)
typedef __attribute__((ext_vector_type(4))) float floatx4;  // MFMA C/D

__device__ __forceinline__ unsigned short f32_to_bf16_rne(float f) {
    unsigned int u = __float_as_uint(f);
    u += 0x7FFFu + ((u >> 16) & 1u);
    return (unsigned short)(u >> 16);
}
__device__ __forceinline__ float bf16_bits_to_f32(unsigned short b) {
    return __uint_as_float(((unsigned int)b) << 16);
}
__device__ __forceinline__ float blo(unsigned int x) { return __uint_as_float(x << 16); }
__device__ __forceinline__ float bhi(unsigned int x) { return __uint_as_float(x & 0xFFFF0000u); }

// ---------------- W (fp32 [K][N]) -> bf16 MFMA-B-fragment order --------------
__global__ __launch_bounds__(256) void convert_w_k(const float* __restrict__ w,
                                                   unsigned short* __restrict__ wsw) {
    int t = blockIdx.x * 256 + threadIdx.x;
    int j     = t & 7;
    int lane  = (t >> 3) & 63;
    int kstep = (t >> 9) & 7;
    int ntile = t >> 12;
    int k = kstep * 32 + (lane >> 4) * 8 + j;
    int n = ntile * 16 + (lane & 15);
    wsw[t] = f32_to_bf16_rne(w[k * D + n]);
}

// ---------------- xw = x @ W (bf16 MFMA), no LDS -----------------------------
// B-frags straight from wsw (128 KB, L2-resident, shared addrs across waves).
// A-frags for all 8 ksteps in 32 VGPRs; one acc tile at a time.
__global__ __launch_bounds__(256, 4) void gemm_xw_k(const float* __restrict__ x,
                                                    const unsigned short* __restrict__ wsw,
                                                    unsigned short* __restrict__ xwb) {
    const int tid  = threadIdx.x;
    const int lane = tid & 63;
    const int wave = tid >> 6;
    const int q    = lane >> 4;
    const int ml   = lane & 15;
    const long rowBase = (long)blockIdx.x * 64 + wave * 16;
    long arow = rowBase + ml;
    if (arow >= N_NODES) arow = 0;
    const float* xr = x + arow * (long)D;

    short8 af[8];
#pragma unroll
    for (int ks = 0; ks < 8; ++ks) {
        const float4 a0 = *(const float4*)(xr + ks * 32 + q * 8);
        const float4 a1 = *(const float4*)(xr + ks * 32 + q * 8 + 4);
        af[ks][0] = (short)f32_to_bf16_rne(a0.x);
        af[ks][1] = (short)f32_to_bf16_rne(a0.y);
        af[ks][2] = (short)f32_to_bf16_rne(a0.z);
        af[ks][3] = (short)f32_to_bf16_rne(a0.w);
        af[ks][4] = (short)f32_to_bf16_rne(a1.x);
        af[ks][5] = (short)f32_to_bf16_rne(a1.y);
        af[ks][6] = (short)f32_to_bf16_rne(a1.z);
        af[ks][7] = (short)f32_to_bf16_rne(a1.w);
    }

    const short8* wf = (const short8*)wsw;

#pragma unroll 4
    for (int nt = 0; nt < 16; ++nt) {
        floatx4 acc = (floatx4){0.f, 0.f, 0.f, 0.f};
#pragma unroll
        for (int ks = 0; ks < 8; ++ks) {
            acc = __builtin_amdgcn_mfma_f32_16x16x32_bf16(
                af[ks], wf[(nt * 8 + ks) * 64 + lane], acc, 0, 0, 0);
        }
#pragma unroll
        for (int r = 0; r < 4; ++r) {
            long orow = rowBase + q * 4 + r;
            if (orow < N_NODES)
                xwb[orow * (long)D + nt * 16 + ml] = f32_to_bf16_rne(acc[r]);
        }
    }
}

// ---------------- per-block bucket histogram (saved, not atomically merged) --
// blockhist[blk*NB + j] = # edges of chunk blk going to bucket j.
__global__ __launch_bounds__(256) void bhist_k(const int* __restrict__ erow,
                                               int* __restrict__ blockhist) {
    __shared__ int h[NB];
    const int tid = threadIdx.x;
    for (int i = tid; i < NB; i += 256) h[i] = 0;
    __syncthreads();
    const int s = blockIdx.x * FILL_CH;
    const int e = min(s + FILL_CH, N_EDGES);
    for (int i = s + tid; i < e; i += 256) atomicAdd(&h[erow[i] >> RSH], 1);
    __syncthreads();
    int* row = blockhist + (size_t)blockIdx.x * NB;
    for (int i = tid; i < NB; i += 256) row[i] = h[i];
}

// ---------------- scan: per-bucket totals + per-(block,bucket) prefixes ------
// thread j owns bucket j: serial prefix over the 196 block counts (coalesced
// across threads), then LDS scan over buckets -> bbase.
__global__ __launch_bounds__(512) void bscan_k(const int* __restrict__ blockhist,
                                               int* __restrict__ blockoff,
                                               int* __restrict__ bbase) {
    __shared__ int sc[512];
    const int t = threadIdx.x;
    int run = 0;
    if (t < NB) {
        for (int i = 0; i < NBLK_E; ++i) {
            blockoff[(size_t)i * NB + t] = run;
            run += blockhist[(size_t)i * NB + t];
        }
    }
    sc[t] = run;
    __syncthreads();
    for (int o = 1; o < 512; o <<= 1) {
        int add = (t >= o) ? sc[t - o] : 0;
        __syncthreads();
        sc[t] += add;
        __syncthreads();
    }
    if (t < NB) bbase[t] = sc[t] - run;
    if (t == NB - 1) bbase[NB] = sc[t];
}

// ---------------- bin edges into coarse buckets (deterministic ranges) -------
// rec = row_local<<33 | val_bf16<<17 | col
__global__ __launch_bounds__(256) void binfill_k(const int* __restrict__ erow,
                                                 const int* __restrict__ ecol,
                                                 const float* __restrict__ eval,
                                                 const int* __restrict__ bbase,
                                                 const int* __restrict__ blockoff,
                                                 unsigned long long* __restrict__ recs) {
    __shared__ int lcur[NB];
    const int tid = threadIdx.x;
    const int* boff = blockoff + (size_t)blockIdx.x * NB;
    for (int i = tid; i < NB; i += 256) lcur[i] = bbase[i] + boff[i];
    __syncthreads();
    const int s = blockIdx.x * FILL_CH;
    const int e = min(s + FILL_CH, N_EDGES);
    for (int i = s + tid; i < e; i += 256) {
        int r = erow[i];
        int b = r >> RSH;
        int pos = atomicAdd(&lcur[b], 1);
        unsigned long long rec =
            ((unsigned long long)(r & (RPB - 1)) << 33) |
            ((unsigned long long)f32_to_bf16_rne(eval[i]) << 17) |
            (unsigned int)ecol[i];
        recs[pos] = rec;
    }
}

// ---------------- per-bucket counting sort to full row order -----------------
// one block per bucket (391 blocks); 256 threads = 256 rows/bucket; scatter
// region ~65 KB, L2-resident.
__global__ __launch_bounds__(256) void bsort_k(const int* __restrict__ bbase,
                                               const unsigned long long* __restrict__ recs,
                                               int* __restrict__ offsets,
                                               unsigned int* __restrict__ cs,
                                               unsigned short* __restrict__ vs) {
    __shared__ int hist[RPB];
    __shared__ int cur[RPB];
    __shared__ int sc[RPB];
    const int t = threadIdx.x;
    const int b = blockIdx.x;
    const int base = bbase[b];
    const int endp = bbase[b + 1];

    hist[t] = 0;
    __syncthreads();
    for (int i = base + t; i < endp; i += 256)
        atomicAdd(&hist[(int)(recs[i] >> 33)], 1);
    __syncthreads();

    int hv = hist[t];
    sc[t] = hv;
    __syncthreads();
    for (int o = 1; o < RPB; o <<= 1) {
        int add = (t >= o) ? sc[t - o] : 0;
        __syncthreads();
        sc[t] += add;
        __syncthreads();
    }
    int excl = sc[t] - hv;
    cur[t] = excl;
    {
        int r = (b << RSH) + t;
        if (r <= N_NODES) offsets[r] = base + excl;
    }
    __syncthreads();

    for (int i = base + t; i < endp; i += 256) {
        unsigned long long rec = recs[i];
        int rl = (int)(rec >> 33);
        int pos = base + atomicAdd(&cur[rl], 1);
        cs[pos] = (unsigned int)(rec & 0x1FFFFu);
        vs[pos] = (unsigned short)((rec >> 17) & 0xFFFFu);
    }
}

// ---------------- segment reduce: out[r] = relu(sum v * xwb[c]) --------------
// one wave per node; paired gathers (2 edges per uint4 wave-load), 4-deep
// straight-line MLP with scalar q0..q3 (NO arrays / NO conditional refill —
// round-5's array+guard variant went to scratch: WRITE_SIZE 100MB->1GB).
// launch_bounds(256,4) lifts the VGPR ceiling to 128 so 4 gathers can coexist.
__global__ __launch_bounds__(256, 4) void aggregate_k(const unsigned short* __restrict__ xwb,
                                                      const int* __restrict__ offsets,
                                                      const unsigned int* __restrict__ cs,
                                                      const unsigned short* __restrict__ vs,
                                                      float* __restrict__ out) {
    const int wave = threadIdx.x >> 6;
    const int lane = threadIdx.x & 63;
    const int r = blockIdx.x * 4 + wave;
    if (r >= N_NODES) return;

    const int start = offsets[r];
    const int end   = offsets[r + 1];
    const int half  = lane >> 5;
    const int hl    = lane & 31;

    float acc[8];
#pragma unroll
    for (int k = 0; k < 8; ++k) acc[k] = 0.f;

    for (int jb = start; jb < end; jb += 64) {
        int j = jb + lane;
        unsigned int c = 0;
        float v = 0.f;
        if (j < end) {
            c = cs[j];
            v = bf16_bits_to_f32(vs[j]);
        }
        const int cnt = min(64, end - jb);
        const int pairs = (cnt + 1) >> 1;
        int t = 0;
        for (; t + 4 <= pairs; t += 4) {
            uint4 q0, q1, q2, q3;
            float b0, b1, b2, b3;
#define SLOT(s, qv, bv)                                                        \
            {                                                                  \
                int src = 2 * (t + (s)) + half;                                \
                int srcc = min(src, cnt - 1);                                  \
                unsigned int bc = (unsigned int)__shfl((int)c, srcc);          \
                float bb = __shfl(v, srcc);                                    \
                bv = (src < cnt) ? bb : 0.f;                                   \
                qv = ((const uint4*)(xwb + (size_t)bc * D))[hl];               \
            }
            SLOT(0, q0, b0)
            SLOT(1, q1, b1)
            SLOT(2, q2, b2)
            SLOT(3, q3, b3)
#undef SLOT
#define FMA8(qv, bv)                                                           \
            acc[0] += bv * blo(qv.x); acc[1] += bv * bhi(qv.x);                \
            acc[2] += bv * blo(qv.y); acc[3] += bv * bhi(qv.y);                \
            acc[4] += bv * blo(qv.z); acc[5] += bv * bhi(qv.z);                \
            acc[6] += bv * blo(qv.w); acc[7] += bv * bhi(qv.w);
            FMA8(q0, b0)
            FMA8(q1, b1)
            FMA8(q2, b2)
            FMA8(q3, b3)
#undef FMA8
        }
        for (; t < pairs; ++t) {
            int src = 2 * t + half;
            int srcc = min(src, cnt - 1);
            unsigned int bc = (unsigned int)__shfl((int)c, srcc);
            float bb = __shfl(v, srcc);
            float bv = (src < cnt) ? bb : 0.f;
            uint4 q = ((const uint4*)(xwb + (size_t)bc * D))[hl];
            acc[0] += bv * blo(q.x); acc[1] += bv * bhi(q.x);
            acc[2] += bv * blo(q.y); acc[3] += bv * bhi(q.y);
            acc[4] += bv * blo(q.z); acc[5] += bv * bhi(q.z);
            acc[6] += bv * blo(q.w); acc[7] += bv * bhi(q.w);
        }
    }

    // combine even/odd halves (lane l and l^32 hold the same columns)
#pragma unroll
    for (int k = 0; k < 8; ++k) acc[k] += __shfl_xor(acc[k], 32);

    // redistribute: lane l writes cols 4l..4l+3 (source lane l>>1)
    const int s = lane >> 1;
    const int par = lane & 1;
    float4 o;
    {
        float a0 = __shfl(acc[0], s), b0 = __shfl(acc[4], s);
        float a1 = __shfl(acc[1], s), b1 = __shfl(acc[5], s);
        float a2 = __shfl(acc[2], s), b2 = __shfl(acc[6], s);
        float a3 = __shfl(acc[3], s), b3 = __shfl(acc[7], s);
        o.x = par ? b0 : a0;
        o.y = par ? b1 : a1;
        o.z = par ? b2 : a2;
        o.w = par ? b3 : a3;
    }
    o.x = fmaxf(o.x, 0.f);
    o.y = fmaxf(o.y, 0.f);
    o.z = fmaxf(o.z, 0.f);
    o.w = fmaxf(o.w, 0.f);
    ((float4*)(out + (size_t)r * D))[lane] = o;
}

extern "C" void kernel_launch(void* const* d_in, const int* in_sizes, int n_in,
                              void* d_out, int out_size, void* d_ws, size_t ws_size,
                              hipStream_t stream) {
    const float* x    = (const float*)d_in[0];
    const float* w    = (const float*)d_in[1];
    const int*   erow = (const int*)d_in[2];
    const int*   ecol = (const int*)d_in[3];
    const float* eval = (const float*)d_in[4];
    float* out = (float*)d_out;

    // ---- workspace layout (~97 MB) ----
    char* p = (char*)d_ws;
    auto align = [](size_t v) { return (v + 255) & ~(size_t)255; };

    unsigned short* xwb = (unsigned short*)p;                  // 51.2 MB
    p += align((size_t)N_NODES * D * sizeof(unsigned short));
    unsigned short* wsw = (unsigned short*)p;                  // 128 KiB
    p += align((size_t)D * D * sizeof(unsigned short));
    int* bbase = (int*)p;  p += align((size_t)(NB + 1) * sizeof(int));
    int* blockhist = (int*)p;  p += align((size_t)NBLK_E * NB * sizeof(int)); // 306 KB
    int* blockoff  = (int*)p;  p += align((size_t)NBLK_E * NB * sizeof(int)); // 306 KB
    unsigned long long* recs = (unsigned long long*)p;         // 25.6 MB
    p += align((size_t)N_EDGES * sizeof(unsigned long long));
    unsigned int*   cs = (unsigned int*)p;    p += align((size_t)N_EDGES * 4);  // 12.8 MB
    unsigned short* vs = (unsigned short*)p;  p += align((size_t)N_EDGES * 2);  // 6.4 MB
    int* offsets = (int*)p;  p += align((size_t)(N_NODES + 1) * sizeof(int));   // 400 KB

    convert_w_k<<<(D * D) / 256, 256, 0, stream>>>(w, wsw);
    gemm_xw_k<<<(N_NODES + 63) / 64, 256, 0, stream>>>(x, wsw, xwb);
    bhist_k<<<NBLK_E, 256, 0, stream>>>(erow, blockhist);
    bscan_k<<<1, 512, 0, stream>>>(blockhist, blockoff, bbase);
    binfill_k<<<NBLK_E, 256, 0, stream>>>(erow, ecol, eval, bbase, blockoff, recs);
    bsort_k<<<NB, 256, 0, stream>>>(bbase, recs, offsets, cs, vs);
    aggregate_k<<<(N_NODES + 3) / 4, 256, 0, stream>>>(xwb, offsets, cs, vs, out);
}